// Round 11
// baseline (136.304 us; speedup 1.0000x reference)
//
#include <hip/hip_runtime.h>
#include <math.h>

#define N_EMBD    4096
#define N_EXPERTS 64
#define N_TOKENS  16384
#define TAU       1e-3f
#define BM        16                  // tokens per block
#define BK        128                 // K per tile
#define NTILES    (N_EMBD / BK)       // 32
#define TILE_B    8192                // f32 A-tile: 16 rows x 512 B

typedef __attribute__((ext_vector_type(8))) short bf16x8;
typedef __attribute__((ext_vector_type(4))) float f32x4;
typedef __attribute__((ext_vector_type(4))) unsigned u32x4;

#define MFMA16 __builtin_amdgcn_mfma_f32_16x16x32_bf16

struct hl_pair { unsigned h, l; };

// ---------------------------------------------------------------------------
// f32 -> (bf16 hi, bf16 lo) RNE split, pair-packed into one u32 each.
// ---------------------------------------------------------------------------
__device__ __forceinline__ hl_pair split_pair(float f0, float f1) {
    unsigned u0 = __builtin_bit_cast(unsigned, f0);
    unsigned u1 = __builtin_bit_cast(unsigned, f1);
    unsigned r0 = u0 + 0x7FFFu + ((u0 >> 16) & 1u);
    unsigned r1 = u1 + 0x7FFFu + ((u1 >> 16) & 1u);
    hl_pair p;
    p.h = (r0 >> 16) | (r1 & 0xFFFF0000u);
    float h0 = __builtin_bit_cast(float, r0 & 0xFFFF0000u);
    float h1 = __builtin_bit_cast(float, r1 & 0xFFFF0000u);
    float l0 = f0 - h0;
    float l1 = f1 - h1;
    unsigned v0 = __builtin_bit_cast(unsigned, l0);
    unsigned v1 = __builtin_bit_cast(unsigned, l1);
    unsigned s0 = v0 + 0x7FFFu + ((v0 >> 16) & 1u);
    unsigned s1 = v1 + 0x7FFFu + ((v1 >> 16) & 1u);
    p.l = (s0 >> 16) | (s1 & 0xFFFF0000u);
    return p;
}

// ---------------------------------------------------------------------------
// Split 8 f32 (two f32x4) into hi/lo bf16x8 fragments.
// ---------------------------------------------------------------------------
__device__ __forceinline__ void split_tile(f32x4 A0, f32x4 A1,
                                           bf16x8& ah, bf16x8& al) {
    u32x4 hu, lu;
    hl_pair p;
    p = split_pair(A0.x, A0.y); hu.x = p.h; lu.x = p.l;
    p = split_pair(A0.z, A0.w); hu.y = p.h; lu.y = p.l;
    p = split_pair(A1.x, A1.y); hu.z = p.h; lu.z = p.l;
    p = split_pair(A1.z, A1.w); hu.w = p.h; lu.w = p.l;
    ah = __builtin_bit_cast(bf16x8, hu);
    al = __builtin_bit_cast(bf16x8, lu);
}

// ---------------------------------------------------------------------------
// 16B global->LDS DMA (per-lane global src, wave-uniform LDS base).
// ---------------------------------------------------------------------------
__device__ __forceinline__ void async_copy16(void* lds_dst, const void* gsrc) {
    __builtin_amdgcn_global_load_lds(
        (const __attribute__((address_space(1))) unsigned int*)gsrc,
        (__attribute__((address_space(3))) unsigned int*)lds_dst,
        16, 0, 0);
}

// ---------------------------------------------------------------------------
// Kernel 0: pack W into bf16 hi/lo MFMA B-fragments; zero the flag counter.
// Frag F = ks*8 + nt*2 + term. Lane l elem j = W[nt*16+(l&15)][ks*32+(l>>4)*8+j]
// ---------------------------------------------------------------------------
__global__ void w_pack_bf16(const float* __restrict__ W,
                            uint4* __restrict__ Bpack,
                            int* __restrict__ flags) {
    int tid = blockIdx.x * blockDim.x + threadIdx.x;   // 32768
    if (tid == 0) flags[0] = 0;
    int lane = tid & 63;
    int nt   = (tid >> 6) & 3;
    int ks   = tid >> 8;                               // 0..127
    int e = nt * 16 + (lane & 15);
    int k = ks * 32 + ((lane >> 4) << 3);
    const float* src = W + (size_t)e * N_EMBD + k;
    uint4 hp, lp;
    hl_pair p0 = split_pair(src[0], src[1]);
    hl_pair p1 = split_pair(src[2], src[3]);
    hl_pair p2 = split_pair(src[4], src[5]);
    hl_pair p3 = split_pair(src[6], src[7]);
    hp.x = p0.h; lp.x = p0.l;
    hp.y = p1.h; lp.y = p1.l;
    hp.z = p2.h; lp.z = p2.l;
    hp.w = p3.h; lp.w = p3.l;
    size_t F = (size_t)ks * 8 + nt * 2;
    Bpack[F * 64 + lane]       = hp;
    Bpack[(F + 1) * 64 + lane] = lp;
}

// ---------------------------------------------------------------------------
// Kernel 1: fused router — A staged as raw f32 via global_load_lds DMA,
// triple-buffered (2-tile prefetch), counted vmcnt(2) before each barrier
// (DMA stays in flight across barriers). bf16 hi/lo split done on read.
// LDS bank spread: DMA source addresses are pre-swizzled (m173) with
// logical^((row&7)<<4); reads apply the same XOR.
// Block = 16 tokens x 4 waves; wave w owns experts [w*16, w*16+16) and
// stages rows [4w, 4w+4) of each A-tile (2 x 1KB DMA per tile).
// ---------------------------------------------------------------------------
__global__ __launch_bounds__(256, 4) void router_fused(
        const float* __restrict__ x,
        const uint4* __restrict__ Bpack,
        float* __restrict__ out,
        int* __restrict__ flags) {
    __shared__ __align__(16) char ldsA[3 * TILE_B];   // 3 x f32 A-tile
    __shared__ float red[BM][64];

    const int tid  = threadIdx.x;
    const int lane = tid & 63;
    const int w    = tid >> 6;                  // wave = expert quarter
    const int tok0 = blockIdx.x * BM;
    const int l15 = lane & 15, l16 = lane >> 4;

    // --- DMA source mapping (pre-swizzled): phys byte P in tile holds
    // logical (row = P>>9, col = (P&511) ^ ((row&7)<<4)).
    const int P0   = w * 2048 + lane * 16;
    const int P1   = P0 + 1024;
    const int row0 = P0 >> 9;
    const int row1 = P1 >> 9;
    const int c0   = (P0 & 511) ^ ((row0 & 7) << 4);
    const int c1   = (P1 & 511) ^ ((row1 & 7) << 4);
    const float* gA0 = x + (size_t)(tok0 + row0) * N_EMBD + (c0 >> 2);
    const float* gA1 = x + (size_t)(tok0 + row1) * N_EMBD + (c1 >> 2);

    // --- fragment read offsets (same XOR on full logical address)
    const int swz_r = (l15 & 7) << 4;
    int roff[8];
#pragma unroll
    for (int ksl = 0; ksl < 4; ++ksl) {
        roff[2 * ksl]     = l15 * 512 + ((l16 * 32 + ksl * 128)      ^ swz_r);
        roff[2 * ksl + 1] = l15 * 512 + ((l16 * 32 + ksl * 128 + 16) ^ swz_r);
    }

    f32x4 acc = {0.f, 0.f, 0.f, 0.f};

    // prologue: DMA tiles 0 and 1; wait tile 0 (counted: tile 1 stays in flight)
    async_copy16(ldsA + 0 * TILE_B + w * 2048,        gA0);
    async_copy16(ldsA + 0 * TILE_B + w * 2048 + 1024, gA1);
    async_copy16(ldsA + 1 * TILE_B + w * 2048,        gA0 + 128);
    async_copy16(ldsA + 1 * TILE_B + w * 2048 + 1024, gA1 + 128);
    asm volatile("s_waitcnt vmcnt(2)" ::: "memory");
    __builtin_amdgcn_s_barrier();
    __builtin_amdgcn_sched_barrier(0);

    for (int t = 0; t < NTILES; ++t) {
        char* bufR = ldsA + (t % 3) * TILE_B;
        char* bufW = ldsA + ((t + 2) % 3) * TILE_B;

        // B fragments (issued BEFORE the DMA so B-waits leave DMA in flight)
        const uint4* bq = Bpack + ((size_t)(t * 4) * 8 + w * 2) * 64 + lane;
        uint4 bh0 = bq[0];    uint4 bl0 = bq[64];
        uint4 bh1 = bq[512];  uint4 bl1 = bq[576];
        uint4 bh2 = bq[1024]; uint4 bl2 = bq[1088];
        uint4 bh3 = bq[1536]; uint4 bl3 = bq[1600];

        // DMA tile t+2
        if (t + 2 < NTILES) {
            async_copy16(bufW + w * 2048,        gA0 + (t + 2) * 128);
            async_copy16(bufW + w * 2048 + 1024, gA1 + (t + 2) * 128);
        }

        bf16x8 ah, al;
        f32x4 a0, a1;
        a0 = *(const f32x4*)(bufR + roff[0]);
        a1 = *(const f32x4*)(bufR + roff[1]);
        split_tile(a0, a1, ah, al);
        acc = MFMA16(ah, __builtin_bit_cast(bf16x8, bh0), acc, 0, 0, 0);
        acc = MFMA16(ah, __builtin_bit_cast(bf16x8, bl0), acc, 0, 0, 0);
        acc = MFMA16(al, __builtin_bit_cast(bf16x8, bh0), acc, 0, 0, 0);
        a0 = *(const f32x4*)(bufR + roff[2]);
        a1 = *(const f32x4*)(bufR + roff[3]);
        split_tile(a0, a1, ah, al);
        acc = MFMA16(ah, __builtin_bit_cast(bf16x8, bh1), acc, 0, 0, 0);
        acc = MFMA16(ah, __builtin_bit_cast(bf16x8, bl1), acc, 0, 0, 0);
        acc = MFMA16(al, __builtin_bit_cast(bf16x8, bh1), acc, 0, 0, 0);
        a0 = *(const f32x4*)(bufR + roff[4]);
        a1 = *(const f32x4*)(bufR + roff[5]);
        split_tile(a0, a1, ah, al);
        acc = MFMA16(ah, __builtin_bit_cast(bf16x8, bh2), acc, 0, 0, 0);
        acc = MFMA16(ah, __builtin_bit_cast(bf16x8, bl2), acc, 0, 0, 0);
        acc = MFMA16(al, __builtin_bit_cast(bf16x8, bh2), acc, 0, 0, 0);
        a0 = *(const f32x4*)(bufR + roff[6]);
        a1 = *(const f32x4*)(bufR + roff[7]);
        split_tile(a0, a1, ah, al);
        acc = MFMA16(ah, __builtin_bit_cast(bf16x8, bh3), acc, 0, 0, 0);
        acc = MFMA16(ah, __builtin_bit_cast(bf16x8, bl3), acc, 0, 0, 0);
        acc = MFMA16(al, __builtin_bit_cast(bf16x8, bh3), acc, 0, 0, 0);

        // counted wait: ensure tile t+1 DMA landed; tile t+2 stays in flight
        if (t < NTILES - 2) {
            asm volatile("s_waitcnt vmcnt(2)" ::: "memory");
            __builtin_amdgcn_s_barrier();
            __builtin_amdgcn_sched_barrier(0);
        } else if (t == NTILES - 2) {
            asm volatile("s_waitcnt vmcnt(0)" ::: "memory");
            __builtin_amdgcn_s_barrier();
            __builtin_amdgcn_sched_barrier(0);
        }
    }

    // C layout: row(token) = (lane>>4)*4 + reg, col(expert in quarter) = lane&15
    const int rb = l16 << 2;
#pragma unroll
    for (int j = 0; j < 4; ++j)
        red[rb + j][w * 16 + l15] = acc[j];
    __syncthreads();

    // wave w finalizes tokens w*4 .. w*4+3; lane = expert
    for (int tt = 0; tt < 4; ++tt) {
        const int t = w * 4 + tt;
        float v = red[t][lane];

        float m1 = v; int i1 = lane;
#pragma unroll
        for (int off = 32; off; off >>= 1) {
            float ov = __shfl_xor(m1, off); int oi = __shfl_xor(i1, off);
            if (ov > m1 || (ov == m1 && oi < i1)) { m1 = ov; i1 = oi; }
        }
        float m2 = (lane == i1) ? -INFINITY : v; int i2 = lane;
#pragma unroll
        for (int off = 32; off; off >>= 1) {
            float ov = __shfl_xor(m2, off); int oi = __shfl_xor(i2, off);
            if (ov > m2 || (ov == m2 && oi < i2)) { m2 = ov; i2 = oi; }
        }
        float m3 = (lane == i1 || lane == i2) ? -INFINITY : v;
#pragma unroll
        for (int off = 32; off; off >>= 1)
            m3 = fmaxf(m3, __shfl_xor(m3, off));

        if (lane == 0) {
            const int tok = tok0 + t;
            float e2  = __expf(m2 - m1);
            float inv = 1.0f / (1.0f + e2);
            float2 idx = make_float2((float)i1, (float)i2);
            float2 gts = make_float2(inv, e2 * inv);
            *(float2*)(out + 2 * tok) = idx;
            *(float2*)(out + 2 * N_TOKENS + 2 * tok) = gts;
            if ((m1 - m2 < TAU) || (m2 - m3 < TAU)) {
                int p = atomicAdd(flags, 1);
                if (p < N_TOKENS) flags[1 + p] = tok;
            }
        }
    }
}

// ---------------------------------------------------------------------------
// Kernel 2: exact f64 refinement of flagged near-tie tokens. Block per token
// (grid-strided). Wave wv handles experts wv*16..+16, lanes split K.
// ---------------------------------------------------------------------------
__global__ __launch_bounds__(256) void refine(const float* __restrict__ x,
                                              const float* __restrict__ W,
                                              const int* __restrict__ flags,
                                              float* __restrict__ out) {
    __shared__ double redd[64];
    const int lane = threadIdx.x & 63;
    const int wv   = threadIdx.x >> 6;
    int cnt = flags[0];
    if (cnt > N_TOKENS) cnt = N_TOKENS;

    for (int i = blockIdx.x; i < cnt; i += gridDim.x) {
        const int tok = flags[1 + i];
        const float4* xr4 = (const float4*)(x + (size_t)tok * N_EMBD);
#pragma unroll
        for (int ee = 0; ee < 16; ++ee) {
            const int e = wv * 16 + ee;
            const float4* wr = (const float4*)(W + (size_t)e * N_EMBD);
            double acc = 0.0;
#pragma unroll 4
            for (int c = 0; c < 16; ++c) {
                float4 xv = xr4[c * 64 + lane];
                float4 wq = wr[c * 64 + lane];
                acc += (double)xv.x * wq.x + (double)xv.y * wq.y
                     + (double)xv.z * wq.z + (double)xv.w * wq.w;
            }
#pragma unroll
            for (int off = 32; off; off >>= 1)
                acc += __shfl_xor(acc, off);
            if (lane == 0) redd[e] = acc;
        }
        __syncthreads();
        if (wv == 0) {
            double v = redd[lane];
            double m1 = v; int i1 = lane;
#pragma unroll
            for (int off = 32; off; off >>= 1) {
                double ov = __shfl_xor(m1, off); int oi = __shfl_xor(i1, off);
                if (ov > m1 || (ov == m1 && oi < i1)) { m1 = ov; i1 = oi; }
            }
            double m2 = (lane == i1) ? -INFINITY : v; int i2 = lane;
#pragma unroll
            for (int off = 32; off; off >>= 1) {
                double ov = __shfl_xor(m2, off); int oi = __shfl_xor(i2, off);
                if (ov > m2 || (ov == m2 && oi < i2)) { m2 = ov; i2 = oi; }
            }
            if (lane == 0) {
                double e2  = exp(m2 - m1);
                double inv = 1.0 / (1.0 + e2);
                out[2 * tok + 0] = (float)i1;
                out[2 * tok + 1] = (float)i2;
                out[2 * N_TOKENS + 2 * tok + 0] = (float)inv;
                out[2 * N_TOKENS + 2 * tok + 1] = (float)(e2 * inv);
            }
        }
        __syncthreads();
    }
}

// ---------------------------------------------------------------------------
extern "C" void kernel_launch(void* const* d_in, const int* in_sizes, int n_in,
                              void* d_out, int out_size, void* d_ws, size_t ws_size,
                              hipStream_t stream) {
    const float* x = (const float*)d_in[0];
    const float* W = (const float*)d_in[1];
    float* out = (float*)d_out;

    uint4* Bpack = (uint4*)d_ws;                          // [0, 1MB)
    int*   flags = (int*)((char*)d_ws + (2u << 20));      // [2MB, ...)

    w_pack_bf16 <<<128, 256, 0, stream>>>(W, Bpack, flags);
    router_fused<<<N_TOKENS / BM, 256, 0, stream>>>(x, Bpack, out, flags);
    refine      <<<128, 256, 0, stream>>>(x, W, flags, out);
}